// Round 14
// baseline (5917.616 us; speedup 1.0000x reference)
//
#include <hip/hip_runtime.h>
#include <math.h>

// ---------------- problem constants ----------------
#define B_    16
#define S_    512
#define IN_   258
#define ST_   512
#define RD_   128
#define UPD_  404
#define UPH_  202
#define COLS_ 916
#define CPAD_ 920
#define G_MM  10           // matmul blocks per batch (full 640-row dot, 92 cols each)
#define CPB_  92
#define ROLES_ 11          // 10 matmul + 1 memory  (best-measured topology)

typedef unsigned long long u64t;

// ---------------- workspace layout ----------------
#define XPART_F  (8192*CPAD_)                 // floats
#define STTAG_N  ((size_t)B_*513*512)         // u64 {state val, tag}
#define RDTAG_N  ((size_t)B_*513*128)         // u64 {read val, tag}
#define UPTAG_N  ((size_t)B_*2*512)           // u64 {upd val, tag}, double-buffered
#define TAGS_N   (STTAG_N + RDTAG_N + UPTAG_N)

// Relaxed agent-scope 8B atomics: single global_load/store_dwordx2 sc0 sc1
// (LLC-direct, bypass non-coherent L1/L2, truly atomic at 8B).
#define AT_LD64(p)   __hip_atomic_load((p), __ATOMIC_RELAXED, __HIP_MEMORY_SCOPE_AGENT)
#define AT_ST64(p,v) __hip_atomic_store((p), (v), __ATOMIC_RELAXED, __HIP_MEMORY_SCOPE_AGENT)

union VT { u64t u; struct { float v; int t; } s; };
__device__ __forceinline__ u64t packVT(float v, int t){ VT x; x.s.v=v; x.s.t=t; return x.u; }
__device__ __forceinline__ float vtVal(u64t u){ VT x; x.u=u; return x.s.v; }
__device__ __forceinline__ int   vtTag(u64t u){ VT x; x.u=u; return x.s.t; }
__host__ __device__ __forceinline__ float vtValH(u64t u){ VT x; x.u=u; return x.s.v; }

// fused flag+data poll with adaptive backoff:
//   iters 0-15   : pure spin (common case — steady-state waits are short)
//   iters 16-511 : s_sleep(1)  (~64 cyc)  — same as proven R10 behavior
//   iters 512+   : s_sleep(32) (~2048 cyc) — break poll-congestion feedback
__device__ __forceinline__ float pollVal(const u64t* p, int want){
  u64t v = AT_LD64(p);
  int c=0;
  while (vtTag(v) != want){
    if (c >= 512)      __builtin_amdgcn_s_sleep(32);
    else if (c >= 16)  __builtin_amdgcn_s_sleep(1);
    v = AT_LD64(p);
    if (++c > (1<<22)) break;   // safety bail: wrong output rather than hang
  }
  return vtVal(v);
}

struct SmemMM {
  float comb[640];          // [state(512) | read(128)]
  float part[5][CPB_];
};
struct SmemMB {             // memory block module state (conflict-free layout)
  float mem[64*513];        // pad 513: bank rotates by 1/row -> conflict-free both passes
  float wt[2][512];
  float dyn[2][512];
  float wscr[2][512];
  float upd[408];
  float kn[2][64];
  float es[2][64];
  float ad[2][64];
  float rpart[2*8*64];      // [h][g][m]
  float redE[16];
  float redG[16];
  float smalls[20];         // s[2][3],j[2][3],jd[2],gamma[2],beta[2],g[2]
};

__device__ __forceinline__ float sigm(float x){ return 1.f/(1.f+__expf(-x)); }
__device__ __forceinline__ float splus(float x){ return fmaxf(x,0.f)+log1pf(__expf(-fabsf(x))); }

// P2: erase/add memory update fused with read(tnext); tagged read store IS the
// release. One barrier (H) inside; no trailing barrier (next-iter mem reads are
// wave-local or ordered by H; rpart rewritten only after next-iter barriers).
__device__ __forceinline__ void p2_step(SmemMB& S, int bb, int tnext,
    u64t* __restrict__ rdTag, int tid)
{
  const int m=tid&63, g=tid>>6;
  float e0=S.es[0][m], e1=S.es[1][m], a0=S.ad[0][m], a1=S.ad[1][m];
  float r0=0.f, r1=0.f;
  const int base=m*513;
  #pragma unroll 4
  for(int kk=0;kk<64;kk++){
    int n=g*64+kk;
    float w0=S.wt[0][n], w1=S.wt[1][n];
    float v=S.mem[base+n];
    float E=fmaf(e0,w0,e1*w1);
    float A=fmaf(a0,w0,a1*w1);
    v=fmaf(v,-E,v)+A;            // v*(1-E)+A
    S.mem[base+n]=v;
    r0=fmaf(w0,v,r0);
    r1=fmaf(w1,v,r1);
  }
  S.rpart[(0*8+g)*64+m]=r0;
  S.rpart[(1*8+g)*64+m]=r1;
  __syncthreads();               // H: rpart + mem writes visible block-wide
  if(tid<128){
    int h=tid>>6, mm=tid&63;
    float s=0.f;
    #pragma unroll
    for(int gg=0;gg<8;gg++) s+=S.rpart[(h*8+gg)*64+mm];
    AT_ST64(&rdTag[((size_t)(bb*513+tnext))*RD_+tid], packVT(s, tnext+1));
  }
}

// thread-local inverse column norm of S.mem (col = tid); call right after p2_step
__device__ __forceinline__ float colNormInv(const SmemMB& S, int tid){
  float nrm=0.f;
  #pragma unroll 8
  for(int m=0;m<64;m++){ float v=S.mem[m*513+tid]; nrm=fmaf(v,v,nrm); }
  return 1.f/(sqrtf(nrm)+1e-12f);
}

// ---------------- init: zero all tag words; state(0)=ones tag=1 ----------------
__global__ void init_kernel(u64t* __restrict__ stTag, u64t* __restrict__ rdTag,
                            u64t* __restrict__ upTag)
{
  size_t i = (size_t)blockIdx.x*blockDim.x + threadIdx.x;
  if (i < STTAG_N) {
    size_t rem = i % (513*512);
    int t = (int)(rem >> 9);
    stTag[i] = (t==0) ? packVT(1.f, 1) : 0ULL;
  } else if (i < STTAG_N + RDTAG_N) {
    rdTag[i - STTAG_N] = 0ULL;
  } else if (i < TAGS_N) {
    upTag[i - STTAG_N - RDTAG_N] = 0ULL;
  }
}

// ---------------- xpart = X @ W[0:258, state|upd] + bias ----------------
__global__ __launch_bounds__(256) void xpart_kernel(const float* __restrict__ X,
    const float* __restrict__ Ws, const float* __restrict__ Wu,
    const float* __restrict__ bs, const float* __restrict__ bu,
    float* __restrict__ xpart)
{
  __shared__ float Xs[32][65];
  __shared__ float Wsh[32][65];
  const int row0=blockIdx.x*64, c0=blockIdx.y*64;
  const int tid=threadIdx.x, tx=tid&15, ty=tid>>4;
  float acc[4][4]={};
  for(int k0=0;k0<IN_;k0+=32){
    for(int i=tid;i<32*64;i+=256){
      int kk=i&31, tt=i>>5, k=k0+kk;
      Xs[kk][tt]=(k<IN_)?X[(size_t)(row0+tt)*IN_+k]:0.f;
    }
    for(int i=tid;i<32*64;i+=256){
      int cc=i&63, kk=i>>6, k=k0+kk, c=c0+cc;
      float v=0.f;
      if(k<IN_){
        if(c<512) v=Ws[(size_t)k*512+c];
        else if(c<COLS_) v=Wu[(size_t)k*404+(c-512)];
      }
      Wsh[kk][cc]=v;
    }
    __syncthreads();
    #pragma unroll
    for(int kk=0;kk<32;kk++){
      float xv[4],wv[4];
      #pragma unroll
      for(int i=0;i<4;i++) xv[i]=Xs[kk][ty*4+i];
      #pragma unroll
      for(int j=0;j<4;j++) wv[j]=Wsh[kk][tx*4+j];
      #pragma unroll
      for(int i=0;i<4;i++)
        #pragma unroll
        for(int j=0;j<4;j++) acc[i][j]=fmaf(xv[i],wv[j],acc[i][j]);
    }
    __syncthreads();
  }
  #pragma unroll
  for(int i=0;i<4;i++){
    int r=row0+ty*4+i;
    #pragma unroll
    for(int j=0;j<4;j++){
      int c=c0+tx*4+j;
      if(c<COLS_){
        float bias=(c<512)?bs[c]:bu[c-512];
        xpart[(size_t)r*CPAD_+c]=acc[i][j]+bias;
      }
    }
  }
}

// ---------------- deferred output GEMM: out = sigmoid([x,state,read]@Wo + bo) ----------------
__global__ __launch_bounds__(256) void outgemm_kernel(const float* __restrict__ X,
    const u64t* __restrict__ stTag, const u64t* __restrict__ rdTag,
    const float* __restrict__ Wo, const float* __restrict__ bo, float* __restrict__ out)
{
  __shared__ float Cs[32][65];
  __shared__ float Wsh[32][65];
  const int row0=blockIdx.x*64, c0=blockIdx.y*64;
  const int tid=threadIdx.x, tx=tid&15, ty=tid>>4;
  float acc[4][4]={};
  for(int k0=0;k0<898;k0+=32){
    for(int i=tid;i<32*64;i+=256){
      int kk=i&31, tt=i>>5, k=k0+kk, row=row0+tt;
      float v=0.f;
      if(k<258) v=X[(size_t)row*IN_+k];
      else if(k<770){ int b=row>>9,t=row&511; v=vtValH(stTag[((size_t)(b*513+t))*512+(k-258)]); }
      else if(k<898){ int b=row>>9,t=row&511; v=vtValH(rdTag[((size_t)(b*513+t))*128+(k-770)]); }
      Cs[kk][tt]=v;
    }
    for(int i=tid;i<32*64;i+=256){
      int cc=i&63, kk=i>>6, k=k0+kk;
      Wsh[kk][cc]=(k<898)?Wo[(size_t)k*256+(c0+cc)]:0.f;
    }
    __syncthreads();
    #pragma unroll
    for(int kk=0;kk<32;kk++){
      float xv[4],wv[4];
      #pragma unroll
      for(int i=0;i<4;i++) xv[i]=Cs[kk][ty*4+i];
      #pragma unroll
      for(int j=0;j<4;j++) wv[j]=Wsh[kk][tx*4+j];
      #pragma unroll
      for(int i=0;i<4;i++)
        #pragma unroll
        for(int j=0;j<4;j++) acc[i][j]=fmaf(xv[i],wv[j],acc[i][j]);
    }
    __syncthreads();
  }
  #pragma unroll
  for(int i=0;i<4;i++){
    int r=row0+ty*4+i;
    #pragma unroll
    for(int j=0;j<4;j++){
      int c=c0+tx*4+j;
      out[(size_t)r*256+c]=sigm(acc[i][j]+bo[c]);
    }
  }
}

// ---------------- main persistent recurrent kernel ----------------
__global__ __launch_bounds__(512, 1) void main_kernel(
    const float* __restrict__ Ws, const float* __restrict__ Wu,
    const float* __restrict__ xpart, u64t* __restrict__ stTag,
    u64t* __restrict__ rdTag, u64t* __restrict__ upTag)
{
  extern __shared__ char smem[];
  // batch-grouped mapping: batch bb's 11 blocks land on XCD bb%8 under i%8
  // round-robin dispatch (perf heuristic only; correctness placement-free).
  const int bb   = blockIdx.x & 15;
  const int role = blockIdx.x >> 4;
  const int tid  = threadIdx.x;

  if (role < G_MM) {
    // ========== matmul block: split polls, 3 barriers ==========
    SmemMM& S = *(SmemMM*)smem;
    const int c  = tid % CPB_;
    const int rc = tid / CPB_;             // 0..3 state chunks, 4 read chunk, 5 idle
    const int cg = role*CPB_ + c;
    const bool cvalid = (cg < COLS_);
    const float* Wp; int ldw, ci;
    if (cg < 512) { Wp = Ws; ldw = 512; ci = cg; }
    else          { Wp = Wu; ldw = 404; ci = cvalid ? (cg-512) : 0; }
    float wreg[128];
    if (rc < 5) {
      #pragma unroll                       // FULL unroll: static idx -> registers
      for (int j = 0; j < 128; ++j)
        wreg[j] = Wp[(size_t)(258 + rc*128 + j)*ldw + ci];
    }
    for (int t = 0; t < S_; ++t) {
      // prefetch xpart (read-only HBM data, cached path is fine)
      float xp = 0.f;
      if (tid < CPB_ && cvalid) xp = xpart[(size_t)(bb*512 + t)*CPAD_ + cg];
      // state(t): every thread polls its own tagged element
      S.comb[tid] = pollVal(&stTag[((size_t)(bb*513 + t))*512 + tid], t+1);
      __syncthreads();
      float acc = 0.f;
      if (rc < 4) {                         // state rows — overlaps read wait
        const float4* cb = (const float4*)&S.comb[rc*128];
        #pragma unroll
        for (int j4 = 0; j4 < 32; ++j4) {
          float4 cv = cb[j4];
          acc = fmaf(cv.x, wreg[4*j4+0], acc);
          acc = fmaf(cv.y, wreg[4*j4+1], acc);
          acc = fmaf(cv.z, wreg[4*j4+2], acc);
          acc = fmaf(cv.w, wreg[4*j4+3], acc);
        }
      }
      // read(t): tagged poll (critical hop — after the state dot)
      if (tid < RD_)
        S.comb[512 + tid] = pollVal(&rdTag[((size_t)(bb*513 + t))*RD_ + tid], t+1);
      __syncthreads();
      if (rc == 4) {                        // read rows
        const float4* cb = (const float4*)&S.comb[512];
        #pragma unroll
        for (int j4 = 0; j4 < 32; ++j4) {
          float4 cv = cb[j4];
          acc = fmaf(cv.x, wreg[4*j4+0], acc);
          acc = fmaf(cv.y, wreg[4*j4+1], acc);
          acc = fmaf(cv.z, wreg[4*j4+2], acc);
          acc = fmaf(cv.w, wreg[4*j4+3], acc);
        }
      }
      if (rc < 5) S.part[rc][c] = acc;
      __syncthreads();
      if (tid < CPB_ && cvalid) {
        float pre = xp + S.part[0][c] + S.part[1][c] + S.part[2][c]
                       + S.part[3][c] + S.part[4][c];
        if (cg < 512)    // tagged store IS the release — no drain, no flag bump
          AT_ST64(&stTag[((size_t)(bb*513 + t + 1))*512 + cg], packVT(sigm(pre), t+2));
        else
          AT_ST64(&upTag[((size_t)(bb*2 + (t&1)))*512 + (cg-512)], packVT(pre, t+1));
      }
      // no trailing sync: S.part next written only after two syncs of next iter
    }
  } else {
    // ========== memory block: 5 barriers/step (C,D,E,F,G) + H in P2 ==========
    SmemMB& S = *(SmemMB*)smem;
    for (int i = tid; i < 64*513; i += 512) S.mem[i] = 0.01f;
    {
      float o0 = (tid == 0) ? 1.f : 0.f;
      S.wt[0][tid]=o0; S.wt[1][tid]=o0; S.dyn[0][tid]=o0; S.dyn[1][tid]=o0;
    }
    if (tid < 128) { S.es[tid>>6][tid&63]=0.f; S.ad[tid>>6][tid&63]=0.f; }
    __syncthreads();
    // prologue: P2 with zero erase/add == pure read(0) from initial wt/mem
    p2_step(S, bb, 0, rdTag, tid);
    float nrmInv = colNormInv(S, tid);      // off-critical-path norm pass

    for (int t = 0; t < S_-1; ++t) {
      // upd(t): contiguous tagged poll, one RT (flag fused with data)
      if (tid < UPD_)
        S.upd[tid] = pollVal(&upTag[((size_t)(bb*2 + (t&1)))*512 + tid], t+1);
      __syncthreads();                                  // C: upd ready
      if (tid < 128) {                      // es/ad + key normalize (butterfly)
        int h=tid>>6, m=tid&63; const float* u=&S.upd[h*UPH_];
        S.es[h][m]=sigm(u[8+m]);
        S.ad[h][m]=u[72+m];
        float kv=u[136+m];
        float s2=kv*kv;
        #pragma unroll
        for(int o=32;o;o>>=1) s2+=__shfl_xor(s2,o);
        S.kn[h][m]=kv*(1.f/(sqrtf(s2)+1e-12f));
      } else if (tid < 130) {               // concurrent scalar smalls (other wave)
        int h = tid-128; const float* u = &S.upd[h*UPH_];
        float sp0=splus(u[0]), sp1=splus(u[1]), sp2=splus(u[2]);
        float mx=fmaxf(sp0,fmaxf(sp1,sp2));
        float e0=__expf(sp0-mx), e1=__expf(sp1-mx), e2=__expf(sp2-mx);
        float inv=1.f/(e0+e1+e2);
        S.smalls[h*3+0]=e0*inv; S.smalls[h*3+1]=e1*inv; S.smalls[h*3+2]=e2*inv;
        float j0=u[4], j1=u[5], j2=u[6];
        float mj=fmaxf(j0,fmaxf(j1,j2));
        float f0=__expf(j0-mj), f1=__expf(j1-mj), f2=__expf(j2-mj);
        float invj=1.f/(f0+f1+f2);
        S.smalls[6+h*3+0]=f0*invj; S.smalls[6+h*3+1]=f1*invj; S.smalls[6+h*3+2]=f2*invj;
        S.smalls[12+h]=sigm(u[3]);           // jd
        S.smalls[14+h]=1.f+splus(u[7]);      // gamma
        S.smalls[16+h]=splus(u[200]);        // beta
        S.smalls[18+h]=sigm(u[201]);         // g
      }
      __syncthreads();                                  // D: transforms ready
      // ---- P1: cosine scores, skip-max softmax (|score|<=beta, fp32-safe),
      //      mix, shift, sharpen; single-barrier reductions ----
      {
        int n = tid;
        float d0=0.f, d1=0.f;
        #pragma unroll 8
        for (int m=0;m<64;m++){
          float v=S.mem[m*513+n];
          d0=fmaf(S.kn[0][m],v,d0);
          d1=fmaf(S.kn[1][m],v,d1);
        }
        float ex0=__expf(S.smalls[16]*d0*nrmInv), ex1=__expf(S.smalls[17]*d1*nrmInv);
        float sm0=ex0, sm1=ex1;
        #pragma unroll
        for(int o=32;o;o>>=1){ sm0+=__shfl_xor(sm0,o); sm1+=__shfl_xor(sm1,o); }
        if((tid&63)==0){ S.redE[(tid>>6)*2]=sm0; S.redE[(tid>>6)*2+1]=sm1; }
        __syncthreads();                                // E: softmax sums
        sm0=S.redE[0]; sm1=S.redE[1];
        #pragma unroll
        for(int i=1;i<8;i++){ sm0+=S.redE[2*i]; sm1+=S.redE[2*i+1]; }
        float wtk0=ex0/sm0, wtk1=ex1/sm1;
        float jd0=S.smalls[12], jd1=S.smalls[13];
        float g0=S.smalls[18],  g1=S.smalls[19];
        float w0o=S.wt[0][n], w1o=S.wt[1][n];
        float dn0=fmaf(jd0, w0o - S.dyn[0][n], S.dyn[0][n]);
        float dn1=fmaf(jd1, w1o - S.dyn[1][n], S.dyn[1][n]);
        S.dyn[0][n]=dn0; S.dyn[1][n]=dn1;
        float fx=(n==0)?1.f:0.f;
        float wm0=S.smalls[6+0]*w0o + S.smalls[6+1]*dn0 + S.smalls[6+2]*fx;
        float wm1=S.smalls[9+0]*w1o + S.smalls[9+1]*dn1 + S.smalls[9+2]*fx;
        float wc0=fmaf(g0, wtk0-wm0, wm0);
        float wc1=fmaf(g1, wtk1-wm1, wm1);
        S.wscr[0][n]=wc0; S.wscr[1][n]=wc1;
        __syncthreads();                                // F: wscr neighbors
        int np=(n+1)&511, nm=(n-1)&511;
        float wsh0=S.smalls[0]*S.wscr[0][np]+S.smalls[1]*wc0+S.smalls[2]*S.wscr[0][nm];
        float wsh1=S.smalls[3]*S.wscr[1][np]+S.smalls[4]*wc1+S.smalls[5]*S.wscr[1][nm];
        float gam0=S.smalls[14], gam1=S.smalls[15];
        float wp0=(wsh0>0.f)?__expf(gam0*__logf(wsh0)):0.f;
        float wp1=(wsh1>0.f)?__expf(gam1*__logf(wsh1)):0.f;
        float ds0=wp0, ds1=wp1;
        #pragma unroll
        for(int o=32;o;o>>=1){ ds0+=__shfl_xor(ds0,o); ds1+=__shfl_xor(ds1,o); }
        if((tid&63)==0){ S.redG[(tid>>6)*2]=ds0; S.redG[(tid>>6)*2+1]=ds1; }
        __syncthreads();                                // G: sharpen sums
        ds0=S.redG[0]; ds1=S.redG[1];
        #pragma unroll
        for(int i=1;i<8;i++){ ds0+=S.redG[2*i]; ds1+=S.redG[2*i+1]; }
        S.wt[0][n]=wp0/(ds0+1e-12f);
        S.wt[1][n]=wp1/(ds1+1e-12f);
      }
      // wt handoff to P2 is wave-local (thread n writes wt[*][n]; P2 wave g
      // reads cols [64g,64g+64) == its own writes) -> in-wave LDS ordering only
      asm volatile("s_waitcnt lgkmcnt(0)" ::: "memory");
      __builtin_amdgcn_sched_barrier(0);
      // ---- P2: mem update + tagged read(t+1) (barrier H inside); then norms ----
      p2_step(S, bb, t+1, rdTag, tid);
      nrmInv = colNormInv(S, tid);
    }
  }
}

// ---------------- launch ----------------
extern "C" void kernel_launch(void* const* d_in, const int* in_sizes, int n_in,
                              void* d_out, int out_size, void* d_ws, size_t ws_size,
                              hipStream_t stream) {
  (void)in_sizes; (void)n_in; (void)out_size;
  const float* X  = (const float*)d_in[0];
  const float* Ws = (const float*)d_in[1];
  const float* bs = (const float*)d_in[2];
  const float* Wo = (const float*)d_in[3];
  const float* bo = (const float*)d_in[4];
  const float* Wu = (const float*)d_in[5];
  const float* bu = (const float*)d_in[6];
  float* out = (float*)d_out;

  const size_t needed = (size_t)XPART_F*4 + TAGS_N*8;
  if (ws_size < needed) return;   // fail visibly rather than corrupt memory

  float* xpart  = (float*)d_ws;
  u64t*  stTag  = (u64t*)(xpart + XPART_F);   // XPART_F*4 is 8B-aligned
  u64t*  rdTag  = stTag + STTAG_N;
  u64t*  upTag  = rdTag + RDTAG_N;

  hipLaunchKernelGGL(init_kernel, dim3((unsigned)((TAGS_N + 255)/256)), dim3(256), 0, stream,
                     stTag, rdTag, upTag);
  hipLaunchKernelGGL(xpart_kernel, dim3(128, 15), dim3(256), 0, stream, X, Ws, Wu, bs, bu, xpart);

  (void)hipFuncSetAttribute((const void*)main_kernel,
        hipFuncAttributeMaxDynamicSharedMemorySize, (int)sizeof(SmemMB));
  void* kargs[] = { (void*)&Ws, (void*)&Wu, (void*)&xpart, (void*)&stTag,
                    (void*)&rdTag, (void*)&upTag };
  hipLaunchCooperativeKernel((const void*)main_kernel, dim3(B_*ROLES_), dim3(512),
                             kargs, (unsigned)sizeof(SmemMB), stream);

  hipLaunchKernelGGL(outgemm_kernel, dim3(128, 4), dim3(256), 0, stream,
                     X, stTag, rdTag, Wo, bo, out);
}

// Round 15
// 5883.941 us; speedup vs baseline: 1.0057x; 1.0057x over previous
//
#include <hip/hip_runtime.h>
#include <math.h>

// ---------------- problem constants ----------------
#define B_    16
#define S_    512
#define IN_   258
#define ST_   512
#define RD_   128
#define UPD_  404
#define UPH_  202
#define COLS_ 916
#define CPAD_ 920
#define G_MM  10           // matmul blocks per batch (full 640-row dot, 92 cols each)
#define CPB_  92
#define ROLES_ 11          // 10 matmul + 1 memory  (best-measured topology)

typedef unsigned long long u64t;

// ---------------- workspace layout ----------------
#define XPART_F  (8192*CPAD_)                 // floats
#define STTAG_N  ((size_t)B_*513*512)         // u64 {state val, tag}
#define RDTAG_N  ((size_t)B_*513*128)         // u64 {read val, tag}
#define UPTAG_N  ((size_t)B_*2*512)           // u64 {upd val, tag}, double-buffered
#define TAGS_N   (STTAG_N + RDTAG_N + UPTAG_N)

// Relaxed agent-scope 8B atomics: single global_load/store_dwordx2 sc0 sc1
// (LLC-direct, bypass non-coherent L1/L2, truly atomic at 8B).
#define AT_LD64(p)   __hip_atomic_load((p), __ATOMIC_RELAXED, __HIP_MEMORY_SCOPE_AGENT)
#define AT_ST64(p,v) __hip_atomic_store((p), (v), __ATOMIC_RELAXED, __HIP_MEMORY_SCOPE_AGENT)

union VT { u64t u; struct { float v; int t; } s; };
__device__ __forceinline__ u64t packVT(float v, int t){ VT x; x.s.v=v; x.s.t=t; return x.u; }
__device__ __forceinline__ float vtVal(u64t u){ VT x; x.u=u; return x.s.v; }
__device__ __forceinline__ int   vtTag(u64t u){ VT x; x.u=u; return x.s.t; }
__host__ __device__ __forceinline__ float vtValH(u64t u){ VT x; x.u=u; return x.s.v; }

// fused flag+data poll: ONE LLC round trip delivers readiness AND the value
__device__ __forceinline__ float pollVal(const u64t* p, int want){
  u64t v = AT_LD64(p);
  int c=0;
  while (vtTag(v) != want){
    __builtin_amdgcn_s_sleep(1);
    v = AT_LD64(p);
    if (++c > (1<<22)) break;   // safety bail: wrong output rather than hang
  }
  return vtVal(v);
}

struct SmemMM {
  float comb[640];          // [state(512) | read(128)]
  float part[5][CPB_];
};
struct SmemMB {             // memory block module state (conflict-free layout)
  float mem[64*513];        // pad 513: bank rotates by 1/row -> conflict-free both passes
  float wt[2][512];
  float dyn[2][512];
  float wscr[2][512];
  float upd[408];
  float kn[2][64];
  float es[2][64];
  float ad[2][64];
  float rpart[2*8*64];      // [h][g][m]
  float redE[16];
  float redG[16];
  float smalls[20];         // s[2][3],j[2][3],jd[2],gamma[2],beta[2],g[2]
};

__device__ __forceinline__ float sigm(float x){ return 1.f/(1.f+__expf(-x)); }
__device__ __forceinline__ float splus(float x){ return fmaxf(x,0.f)+log1pf(__expf(-fabsf(x))); }

// P2: erase/add memory update fused with read(tnext); tagged read store IS the
// release. One barrier (H) inside; no trailing barrier (next-iter mem reads are
// wave-local or ordered by H; rpart rewritten only after next-iter barriers).
__device__ __forceinline__ void p2_step(SmemMB& S, int bb, int tnext,
    u64t* __restrict__ rdTag, int tid)
{
  const int m=tid&63, g=tid>>6;
  float e0=S.es[0][m], e1=S.es[1][m], a0=S.ad[0][m], a1=S.ad[1][m];
  float r0=0.f, r1=0.f;
  const int base=m*513;
  #pragma unroll 4
  for(int kk=0;kk<64;kk++){
    int n=g*64+kk;
    float w0=S.wt[0][n], w1=S.wt[1][n];
    float v=S.mem[base+n];
    float E=fmaf(e0,w0,e1*w1);
    float A=fmaf(a0,w0,a1*w1);
    v=fmaf(v,-E,v)+A;            // v*(1-E)+A
    S.mem[base+n]=v;
    r0=fmaf(w0,v,r0);
    r1=fmaf(w1,v,r1);
  }
  S.rpart[(0*8+g)*64+m]=r0;
  S.rpart[(1*8+g)*64+m]=r1;
  __syncthreads();               // H: rpart + mem writes visible block-wide
  if(tid<128){
    int h=tid>>6, mm=tid&63;
    float s=0.f;
    #pragma unroll
    for(int gg=0;gg<8;gg++) s+=S.rpart[(h*8+gg)*64+mm];
    AT_ST64(&rdTag[((size_t)(bb*513+tnext))*RD_+tid], packVT(s, tnext+1));
  }
}

// thread-local inverse column norm of S.mem (col = tid); call right after p2_step
__device__ __forceinline__ float colNormInv(const SmemMB& S, int tid){
  float nrm=0.f;
  #pragma unroll 8
  for(int m=0;m<64;m++){ float v=S.mem[m*513+tid]; nrm=fmaf(v,v,nrm); }
  return 1.f/(sqrtf(nrm)+1e-12f);
}

// ---------------- init: zero all tag words; state(0)=ones tag=1 ----------------
__global__ void init_kernel(u64t* __restrict__ stTag, u64t* __restrict__ rdTag,
                            u64t* __restrict__ upTag)
{
  size_t i = (size_t)blockIdx.x*blockDim.x + threadIdx.x;
  if (i < STTAG_N) {
    size_t rem = i % (513*512);
    int t = (int)(rem >> 9);
    stTag[i] = (t==0) ? packVT(1.f, 1) : 0ULL;
  } else if (i < STTAG_N + RDTAG_N) {
    rdTag[i - STTAG_N] = 0ULL;
  } else if (i < TAGS_N) {
    upTag[i - STTAG_N - RDTAG_N] = 0ULL;
  }
}

// ---------------- xpart = X @ W[0:258, state|upd] + bias ----------------
__global__ __launch_bounds__(256) void xpart_kernel(const float* __restrict__ X,
    const float* __restrict__ Ws, const float* __restrict__ Wu,
    const float* __restrict__ bs, const float* __restrict__ bu,
    float* __restrict__ xpart)
{
  __shared__ float Xs[32][65];
  __shared__ float Wsh[32][65];
  const int row0=blockIdx.x*64, c0=blockIdx.y*64;
  const int tid=threadIdx.x, tx=tid&15, ty=tid>>4;
  float acc[4][4]={};
  for(int k0=0;k0<IN_;k0+=32){
    for(int i=tid;i<32*64;i+=256){
      int kk=i&31, tt=i>>5, k=k0+kk;
      Xs[kk][tt]=(k<IN_)?X[(size_t)(row0+tt)*IN_+k]:0.f;
    }
    for(int i=tid;i<32*64;i+=256){
      int cc=i&63, kk=i>>6, k=k0+kk, c=c0+cc;
      float v=0.f;
      if(k<IN_){
        if(c<512) v=Ws[(size_t)k*512+c];
        else if(c<COLS_) v=Wu[(size_t)k*404+(c-512)];
      }
      Wsh[kk][cc]=v;
    }
    __syncthreads();
    #pragma unroll
    for(int kk=0;kk<32;kk++){
      float xv[4],wv[4];
      #pragma unroll
      for(int i=0;i<4;i++) xv[i]=Xs[kk][ty*4+i];
      #pragma unroll
      for(int j=0;j<4;j++) wv[j]=Wsh[kk][tx*4+j];
      #pragma unroll
      for(int i=0;i<4;i++)
        #pragma unroll
        for(int j=0;j<4;j++) acc[i][j]=fmaf(xv[i],wv[j],acc[i][j]);
    }
    __syncthreads();
  }
  #pragma unroll
  for(int i=0;i<4;i++){
    int r=row0+ty*4+i;
    #pragma unroll
    for(int j=0;j<4;j++){
      int c=c0+tx*4+j;
      if(c<COLS_){
        float bias=(c<512)?bs[c]:bu[c-512];
        xpart[(size_t)r*CPAD_+c]=acc[i][j]+bias;
      }
    }
  }
}

// ---------------- deferred output GEMM: out = sigmoid([x,state,read]@Wo + bo) ----------------
__global__ __launch_bounds__(256) void outgemm_kernel(const float* __restrict__ X,
    const u64t* __restrict__ stTag, const u64t* __restrict__ rdTag,
    const float* __restrict__ Wo, const float* __restrict__ bo, float* __restrict__ out)
{
  __shared__ float Cs[32][65];
  __shared__ float Wsh[32][65];
  const int row0=blockIdx.x*64, c0=blockIdx.y*64;
  const int tid=threadIdx.x, tx=tid&15, ty=tid>>4;
  float acc[4][4]={};
  for(int k0=0;k0<898;k0+=32){
    for(int i=tid;i<32*64;i+=256){
      int kk=i&31, tt=i>>5, k=k0+kk, row=row0+tt;
      float v=0.f;
      if(k<258) v=X[(size_t)row*IN_+k];
      else if(k<770){ int b=row>>9,t=row&511; v=vtValH(stTag[((size_t)(b*513+t))*512+(k-258)]); }
      else if(k<898){ int b=row>>9,t=row&511; v=vtValH(rdTag[((size_t)(b*513+t))*128+(k-770)]); }
      Cs[kk][tt]=v;
    }
    for(int i=tid;i<32*64;i+=256){
      int cc=i&63, kk=i>>6, k=k0+kk;
      Wsh[kk][cc]=(k<898)?Wo[(size_t)k*256+(c0+cc)]:0.f;
    }
    __syncthreads();
    #pragma unroll
    for(int kk=0;kk<32;kk++){
      float xv[4],wv[4];
      #pragma unroll
      for(int i=0;i<4;i++) xv[i]=Cs[kk][ty*4+i];
      #pragma unroll
      for(int j=0;j<4;j++) wv[j]=Wsh[kk][tx*4+j];
      #pragma unroll
      for(int i=0;i<4;i++)
        #pragma unroll
        for(int j=0;j<4;j++) acc[i][j]=fmaf(xv[i],wv[j],acc[i][j]);
    }
    __syncthreads();
  }
  #pragma unroll
  for(int i=0;i<4;i++){
    int r=row0+ty*4+i;
    #pragma unroll
    for(int j=0;j<4;j++){
      int c=c0+tx*4+j;
      out[(size_t)r*256+c]=sigm(acc[i][j]+bo[c]);
    }
  }
}

// ---------------- main persistent recurrent kernel ----------------
__global__ __launch_bounds__(512, 1) void main_kernel(
    const float* __restrict__ Ws, const float* __restrict__ Wu,
    const float* __restrict__ xpart, u64t* __restrict__ stTag,
    u64t* __restrict__ rdTag, u64t* __restrict__ upTag)
{
  extern __shared__ char smem[];
  // batch-grouped mapping: batch bb's 11 blocks land on XCD bb%8 under i%8
  // round-robin dispatch (perf heuristic only; correctness placement-free).
  const int bb   = blockIdx.x & 15;
  const int role = blockIdx.x >> 4;
  const int tid  = threadIdx.x;

  if (role < G_MM) {
    // ========== matmul block: split polls, 3 barriers ==========
    // Read poll is done by waves 6-7 (tid 384..511 — no state-dot work),
    // CONCURRENT with the rc<4 state dot: max(dot, detect) not dot+detect.
    SmemMM& S = *(SmemMM*)smem;
    const int c  = tid % CPB_;
    const int rc = tid / CPB_;             // 0..3 state chunks, 4 read chunk, 5 idle
    const int cg = role*CPB_ + c;
    const bool cvalid = (cg < COLS_);
    const float* Wp; int ldw, ci;
    if (cg < 512) { Wp = Ws; ldw = 512; ci = cg; }
    else          { Wp = Wu; ldw = 404; ci = cvalid ? (cg-512) : 0; }
    float wreg[128];
    if (rc < 5) {
      #pragma unroll                       // FULL unroll: static idx -> registers
      for (int j = 0; j < 128; ++j)
        wreg[j] = Wp[(size_t)(258 + rc*128 + j)*ldw + ci];
    }
    for (int t = 0; t < S_; ++t) {
      // prefetch xpart (read-only HBM data, cached path is fine)
      float xp = 0.f;
      if (tid < CPB_ && cvalid) xp = xpart[(size_t)(bb*512 + t)*CPAD_ + cg];
      // state(t): every thread polls its own tagged element
      S.comb[tid] = pollVal(&stTag[((size_t)(bb*513 + t))*512 + tid], t+1);
      __syncthreads();                      // A: state ready
      float acc = 0.f;
      if (rc < 4) {                         // waves 0-5: state dot
        const float4* cb = (const float4*)&S.comb[rc*128];
        #pragma unroll
        for (int j4 = 0; j4 < 32; ++j4) {
          float4 cv = cb[j4];
          acc = fmaf(cv.x, wreg[4*j4+0], acc);
          acc = fmaf(cv.y, wreg[4*j4+1], acc);
          acc = fmaf(cv.z, wreg[4*j4+2], acc);
          acc = fmaf(cv.w, wreg[4*j4+3], acc);
        }
      } else if (tid >= 384) {              // waves 6-7: read poll (overlaps dot)
        S.comb[512 + (tid-384)] =
            pollVal(&rdTag[((size_t)(bb*513 + t))*RD_ + (tid-384)], t+1);
      }
      __syncthreads();                      // B: read ready + dots done
      if (rc == 4) {                        // read rows
        const float4* cb = (const float4*)&S.comb[512];
        #pragma unroll
        for (int j4 = 0; j4 < 32; ++j4) {
          float4 cv = cb[j4];
          acc = fmaf(cv.x, wreg[4*j4+0], acc);
          acc = fmaf(cv.y, wreg[4*j4+1], acc);
          acc = fmaf(cv.z, wreg[4*j4+2], acc);
          acc = fmaf(cv.w, wreg[4*j4+3], acc);
        }
      }
      if (rc < 5) S.part[rc][c] = acc;
      __syncthreads();                      // C: partials
      if (tid < CPB_ && cvalid) {
        float pre = xp + S.part[0][c] + S.part[1][c] + S.part[2][c]
                       + S.part[3][c] + S.part[4][c];
        if (cg < 512)    // tagged store IS the release — no drain, no flag bump
          AT_ST64(&stTag[((size_t)(bb*513 + t + 1))*512 + cg], packVT(sigm(pre), t+2));
        else
          AT_ST64(&upTag[((size_t)(bb*2 + (t&1)))*512 + (cg-512)], packVT(pre, t+1));
      }
      // no trailing sync: comb/part next written only after next iter's barriers
    }
  } else {
    // ========== memory block: 5 barriers/step (C,D,E,F,G) + H in P2 ==========
    SmemMB& S = *(SmemMB*)smem;
    for (int i = tid; i < 64*513; i += 512) S.mem[i] = 0.01f;
    {
      float o0 = (tid == 0) ? 1.f : 0.f;
      S.wt[0][tid]=o0; S.wt[1][tid]=o0; S.dyn[0][tid]=o0; S.dyn[1][tid]=o0;
    }
    if (tid < 128) { S.es[tid>>6][tid&63]=0.f; S.ad[tid>>6][tid&63]=0.f; }
    __syncthreads();
    // prologue: P2 with zero erase/add == pure read(0) from initial wt/mem
    p2_step(S, bb, 0, rdTag, tid);
    float nrmInv = colNormInv(S, tid);      // off-critical-path norm pass

    for (int t = 0; t < S_-1; ++t) {
      // upd(t): contiguous tagged poll, one RT (flag fused with data)
      if (tid < UPD_)
        S.upd[tid] = pollVal(&upTag[((size_t)(bb*2 + (t&1)))*512 + tid], t+1);
      __syncthreads();                                  // C: upd ready
      if (tid < 128) {                      // es/ad + key normalize (butterfly)
        int h=tid>>6, m=tid&63; const float* u=&S.upd[h*UPH_];
        S.es[h][m]=sigm(u[8+m]);
        S.ad[h][m]=u[72+m];
        float kv=u[136+m];
        float s2=kv*kv;
        #pragma unroll
        for(int o=32;o;o>>=1) s2+=__shfl_xor(s2,o);
        S.kn[h][m]=kv*(1.f/(sqrtf(s2)+1e-12f));
      } else if (tid < 130) {               // concurrent scalar smalls (other wave)
        int h = tid-128; const float* u = &S.upd[h*UPH_];
        float sp0=splus(u[0]), sp1=splus(u[1]), sp2=splus(u[2]);
        float mx=fmaxf(sp0,fmaxf(sp1,sp2));
        float e0=__expf(sp0-mx), e1=__expf(sp1-mx), e2=__expf(sp2-mx);
        float inv=1.f/(e0+e1+e2);
        S.smalls[h*3+0]=e0*inv; S.smalls[h*3+1]=e1*inv; S.smalls[h*3+2]=e2*inv;
        float j0=u[4], j1=u[5], j2=u[6];
        float mj=fmaxf(j0,fmaxf(j1,j2));
        float f0=__expf(j0-mj), f1=__expf(j1-mj), f2=__expf(j2-mj);
        float invj=1.f/(f0+f1+f2);
        S.smalls[6+h*3+0]=f0*invj; S.smalls[6+h*3+1]=f1*invj; S.smalls[6+h*3+2]=f2*invj;
        S.smalls[12+h]=sigm(u[3]);           // jd
        S.smalls[14+h]=1.f+splus(u[7]);      // gamma
        S.smalls[16+h]=splus(u[200]);        // beta
        S.smalls[18+h]=sigm(u[201]);         // g
      }
      __syncthreads();                                  // D: transforms ready
      // ---- P1: cosine scores, skip-max softmax (|score|<=beta, fp32-safe),
      //      mix, shift, sharpen; single-barrier reductions ----
      {
        int n = tid;
        float d0=0.f, d1=0.f;
        #pragma unroll 8
        for (int m=0;m<64;m++){
          float v=S.mem[m*513+n];
          d0=fmaf(S.kn[0][m],v,d0);
          d1=fmaf(S.kn[1][m],v,d1);
        }
        float ex0=__expf(S.smalls[16]*d0*nrmInv), ex1=__expf(S.smalls[17]*d1*nrmInv);
        float sm0=ex0, sm1=ex1;
        #pragma unroll
        for(int o=32;o;o>>=1){ sm0+=__shfl_xor(sm0,o); sm1+=__shfl_xor(sm1,o); }
        if((tid&63)==0){ S.redE[(tid>>6)*2]=sm0; S.redE[(tid>>6)*2+1]=sm1; }
        __syncthreads();                                // E: softmax sums
        sm0=S.redE[0]; sm1=S.redE[1];
        #pragma unroll
        for(int i=1;i<8;i++){ sm0+=S.redE[2*i]; sm1+=S.redE[2*i+1]; }
        float wtk0=ex0/sm0, wtk1=ex1/sm1;
        float jd0=S.smalls[12], jd1=S.smalls[13];
        float g0=S.smalls[18],  g1=S.smalls[19];
        float w0o=S.wt[0][n], w1o=S.wt[1][n];
        float dn0=fmaf(jd0, w0o - S.dyn[0][n], S.dyn[0][n]);
        float dn1=fmaf(jd1, w1o - S.dyn[1][n], S.dyn[1][n]);
        S.dyn[0][n]=dn0; S.dyn[1][n]=dn1;
        float fx=(n==0)?1.f:0.f;
        float wm0=S.smalls[6+0]*w0o + S.smalls[6+1]*dn0 + S.smalls[6+2]*fx;
        float wm1=S.smalls[9+0]*w1o + S.smalls[9+1]*dn1 + S.smalls[9+2]*fx;
        float wc0=fmaf(g0, wtk0-wm0, wm0);
        float wc1=fmaf(g1, wtk1-wm1, wm1);
        S.wscr[0][n]=wc0; S.wscr[1][n]=wc1;
        __syncthreads();                                // F: wscr neighbors
        int np=(n+1)&511, nm=(n-1)&511;
        float wsh0=S.smalls[0]*S.wscr[0][np]+S.smalls[1]*wc0+S.smalls[2]*S.wscr[0][nm];
        float wsh1=S.smalls[3]*S.wscr[1][np]+S.smalls[4]*wc1+S.smalls[5]*S.wscr[1][nm];
        float gam0=S.smalls[14], gam1=S.smalls[15];
        float wp0=(wsh0>0.f)?__expf(gam0*__logf(wsh0)):0.f;
        float wp1=(wsh1>0.f)?__expf(gam1*__logf(wsh1)):0.f;
        float ds0=wp0, ds1=wp1;
        #pragma unroll
        for(int o=32;o;o>>=1){ ds0+=__shfl_xor(ds0,o); ds1+=__shfl_xor(ds1,o); }
        if((tid&63)==0){ S.redG[(tid>>6)*2]=ds0; S.redG[(tid>>6)*2+1]=ds1; }
        __syncthreads();                                // G: sharpen sums
        ds0=S.redG[0]; ds1=S.redG[1];
        #pragma unroll
        for(int i=1;i<8;i++){ ds0+=S.redG[2*i]; ds1+=S.redG[2*i+1]; }
        S.wt[0][n]=wp0/(ds0+1e-12f);
        S.wt[1][n]=wp1/(ds1+1e-12f);
      }
      // wt handoff to P2 is wave-local (thread n writes wt[*][n]; P2 wave g
      // reads cols [64g,64g+64) == its own writes) -> in-wave LDS ordering only
      asm volatile("s_waitcnt lgkmcnt(0)" ::: "memory");
      __builtin_amdgcn_sched_barrier(0);
      // ---- P2: mem update + tagged read(t+1) (barrier H inside); then norms ----
      p2_step(S, bb, t+1, rdTag, tid);
      nrmInv = colNormInv(S, tid);
    }
  }
}

// ---------------- launch ----------------
extern "C" void kernel_launch(void* const* d_in, const int* in_sizes, int n_in,
                              void* d_out, int out_size, void* d_ws, size_t ws_size,
                              hipStream_t stream) {
  (void)in_sizes; (void)n_in; (void)out_size;
  const float* X  = (const float*)d_in[0];
  const float* Ws = (const float*)d_in[1];
  const float* bs = (const float*)d_in[2];
  const float* Wo = (const float*)d_in[3];
  const float* bo = (const float*)d_in[4];
  const float* Wu = (const float*)d_in[5];
  const float* bu = (const float*)d_in[6];
  float* out = (float*)d_out;

  const size_t needed = (size_t)XPART_F*4 + TAGS_N*8;
  if (ws_size < needed) return;   // fail visibly rather than corrupt memory

  float* xpart  = (float*)d_ws;
  u64t*  stTag  = (u64t*)(xpart + XPART_F);   // XPART_F*4 is 8B-aligned
  u64t*  rdTag  = stTag + STTAG_N;
  u64t*  upTag  = rdTag + RDTAG_N;

  hipLaunchKernelGGL(init_kernel, dim3((unsigned)((TAGS_N + 255)/256)), dim3(256), 0, stream,
                     stTag, rdTag, upTag);
  hipLaunchKernelGGL(xpart_kernel, dim3(128, 15), dim3(256), 0, stream, X, Ws, Wu, bs, bu, xpart);

  (void)hipFuncSetAttribute((const void*)main_kernel,
        hipFuncAttributeMaxDynamicSharedMemorySize, (int)sizeof(SmemMB));
  void* kargs[] = { (void*)&Ws, (void*)&Wu, (void*)&xpart, (void*)&stTag,
                    (void*)&rdTag, (void*)&upTag };
  hipLaunchCooperativeKernel((const void*)main_kernel, dim3(B_*ROLES_), dim3(512),
                             kargs, (unsigned)sizeof(SmemMB), stream);

  hipLaunchKernelGGL(outgemm_kernel, dim3(128, 4), dim3(256), 0, stream,
                     X, stTag, rdTag, Wo, bo, out);
}